// Round 1
// baseline (1670.944 us; speedup 1.0000x reference)
//
#include <hip/hip_runtime.h>

typedef __attribute__((ext_vector_type(8))) short short8;
typedef __attribute__((ext_vector_type(8))) unsigned short ushort8;
typedef __attribute__((ext_vector_type(4))) float f32x4;

#define K_DIM 70400   // 275 groups * 256 ci ; group g = v*5+kw
#define XROWS 118     // padded rows: xrow in [-25, 92] -> r = xrow+25
#define XCOLS 68      // padded cols: xcol in [-2, 65]  -> c = xcol+2

// ws layout
#define XPACK_ELEMS (8 * XROWS * XCOLS * 256)          // 16,433,152 bf16
#define XPACK_BYTES (XPACK_ELEMS * 2)                  // 32,866,304
#define APACK_ELEMS (256 * K_DIM)                      // 18,022,400 bf16
#define APACK_BYTES (APACK_ELEMS * 2)                  // 36,044,800

static __device__ __forceinline__ unsigned short f2bf(float f) {
    unsigned u = __builtin_bit_cast(unsigned, f);
    u += 0x7fffu + ((u >> 16) & 1u);
    return (unsigned short)(u >> 16);
}

static __device__ __forceinline__ void mfma16(f32x4& acc, short8 a, short8 b) {
    asm("v_mfma_f32_16x16x32_bf16 %0, %1, %2, %0" : "+v"(acc) : "v"(a), "v"(b));
}

#define GLOAD_LDS(gp, lp) __builtin_amdgcn_global_load_lds( \
    (const __attribute__((address_space(1))) void*)(gp),    \
    (__attribute__((address_space(3))) void*)(lp), 16, 0, 0)

// ---------------- pack kernels ----------------

__global__ __launch_bounds__(256) void zero_ws_kernel(ushort8* __restrict__ p, int n) {
    int i = blockIdx.x * 256 + threadIdx.x;
    if (i < n) { ushort8 z = {}; p[i] = z; }
}

// xpack[b][r][c][ci] bf16, zero borders; interior r=25..88 (xrow 0..63), c=2..65
__global__ __launch_bounds__(256) void pack_x_kernel(const float* __restrict__ x,
                                                     unsigned short* __restrict__ xp) {
    int g = blockIdx.x * 256 + threadIdx.x;   // 1,048,576 threads
    int xc = g & 63;
    int rest = g >> 6;
    int chunk = rest & 31;        // ci chunk of 8
    int br = rest >> 5;
    int xr = br & 63;
    int b  = br >> 6;
    const float* src = x + (long)(b * 256 + chunk * 8) * 4096 + xr * 64 + xc;
    ushort8 o;
#pragma unroll
    for (int e = 0; e < 8; ++e) o[e] = f2bf(src[(long)e * 4096]);
    long off = ((long)((b * XROWS + xr + 25) * XCOLS + (xc + 2))) * 256 + chunk * 8;
    *(ushort8*)(xp + off) = o;
}

// Apack[c][k], k = (idx*25 + kh*5 + kw)*256 + ci  (== (v*5+kw)*256+ci, v=5idx+kh)
__global__ __launch_bounds__(256) void pack_w_kernel(const float* __restrict__ W,
                                                     unsigned short* __restrict__ Apk) {
    int c = blockIdx.x, t = threadIdx.x;
    __shared__ float lw[6400];
    for (int idx = 0; idx < 11; ++idx) {
        const float* src = W + (long)(c * 11 + idx) * 6400;
        for (int e = t; e < 6400; e += 256) lw[e] = src[e];
        __syncthreads();
        // thread t == ci
#pragma unroll 5
        for (int khw = 0; khw < 25; ++khw)
            Apk[(long)c * K_DIM + (idx * 25 + khw) * 256 + t] = f2bf(lw[t * 25 + khw]);
        __syncthreads();
    }
}

// ---------------- GEMM: out_pre[c][n] = sum_k Apack[c][k] * B[k][n] ----------------
// n = (b*64 + i)*64 + j ; B[k][n] = xpack[b][i+v][j+kw][ci], k = g*256+ci, g=v*5+kw
__global__ __launch_bounds__(256) void gemm_kernel(const unsigned short* __restrict__ Apk,
                                                   const unsigned short* __restrict__ Xpk,
                                                   float* __restrict__ out) {
    __shared__ unsigned short ldsA[128 * 64];
    __shared__ unsigned short ldsB[128 * 64];
    const int t = threadIdx.x;
    const int bid = blockIdx.x;
    const int mt = bid >> 8;          // 0..1
    const int nt = bid & 255;         // 0..255
    const int m0 = mt * 128;
    const int n0 = nt * 128;

    int baseA[4], baseB[4];
#pragma unroll
    for (int p = 0; p < 4; ++p) {
        int ch = p * 256 + t;         // chunk 0..1023 : 16B each
        int r = ch >> 3, s = ch & 7;
        baseA[p] = (m0 + r) * K_DIM + s * 8;
        int n = n0 + r;
        int b = n >> 12, i = (n >> 6) & 63, j = n & 63;
        baseB[p] = ((b * XROWS + i) * XCOLS + j) * 256 + s * 8;
    }

    f32x4 acc[4][4] = {};
    const int lane = t & 63;
    const int w = t >> 6;
    const int wr = (w >> 1) * 64;
    const int wc = (w & 1) * 64;
    const int lrow = lane & 15;
    const int lk = (lane >> 4) * 8;

    for (int kt = 0; kt < 1100; ++kt) {
        int g = kt >> 2;
        int ci0 = (kt & 3) << 6;
        int v = g / 5;
        int kw = g - v * 5;
        int dB = (v * XCOLS + kw) * 256 + ci0;
        int dA = kt << 6;
#pragma unroll
        for (int p = 0; p < 4; ++p)
            GLOAD_LDS(Apk + baseA[p] + dA, ldsA + (p * 256 + t) * 8);
#pragma unroll
        for (int p = 0; p < 4; ++p)
            GLOAD_LDS(Xpk + baseB[p] + dB, ldsB + (p * 256 + t) * 8);
        __syncthreads();   // compiler drains vmcnt before s_barrier -> LDS ready
#pragma unroll
        for (int kk = 0; kk < 2; ++kk) {
            short8 af[4], bf[4];
#pragma unroll
            for (int m = 0; m < 4; ++m)
                af[m] = *(const short8*)(ldsA + (wr + m * 16 + lrow) * 64 + kk * 32 + lk);
#pragma unroll
            for (int n = 0; n < 4; ++n)
                bf[n] = *(const short8*)(ldsB + (wc + n * 16 + lrow) * 64 + kk * 32 + lk);
#pragma unroll
            for (int m = 0; m < 4; ++m)
#pragma unroll
                for (int n = 0; n < 4; ++n)
                    mfma16(acc[m][n], af[m], bf[n]);
        }
        __syncthreads();
    }

    // epilogue: C/D layout col=lane&15, row=(lane>>4)*4+reg  [m89]
    const int b = n0 >> 12;
    const int inb = n0 & 4095;        // tile never crosses batch (4096 % 128 == 0)
    float* ob = out + (long)b * 1048576 + inb + wc + (lane & 15);
#pragma unroll
    for (int m = 0; m < 4; ++m) {
#pragma unroll
        for (int q = 0; q < 4; ++q) {
            int row = m0 + wr + m * 16 + (lane >> 4) * 4 + q;
            float* orow = ob + (long)row * 4096;
#pragma unroll
            for (int n = 0; n < 4; ++n)
                orow[n * 16] = acc[m][n][q];
        }
    }
}

// ---------------- BatchNorm ----------------

__global__ __launch_bounds__(256) void bn_stats_kernel(const float* __restrict__ out,
                                                       const float* __restrict__ gamma,
                                                       const float* __restrict__ beta,
                                                       float* __restrict__ bnp) {
    int c = blockIdx.x, t = threadIdx.x;
    float s = 0.f, q = 0.f;
    for (int b = 0; b < 8; ++b) {
        const float* p = out + (long)b * 1048576 + (long)c * 4096;
        for (int e = t; e < 4096; e += 256) { float v = p[e]; s += v; q += v * v; }
    }
#pragma unroll
    for (int off = 32; off > 0; off >>= 1) { s += __shfl_down(s, off); q += __shfl_down(q, off); }
    __shared__ float ls[4], lq[4];
    int w = t >> 6;
    if ((t & 63) == 0) { ls[w] = s; lq[w] = q; }
    __syncthreads();
    if (t == 0) {
        s = ls[0] + ls[1] + ls[2] + ls[3];
        q = lq[0] + lq[1] + lq[2] + lq[3];
        float mean = s * (1.f / 32768.f);
        float var = q * (1.f / 32768.f) - mean * mean;
        float sc = gamma[c] * rsqrtf(var + 1e-5f);
        bnp[c] = sc;
        bnp[256 + c] = beta[c] - mean * sc;
    }
}

__global__ __launch_bounds__(256) void bn_apply_kernel(float* __restrict__ out,
                                                       const float* __restrict__ bnp) {
    int i = blockIdx.x * 256 + threadIdx.x;   // 2,097,152 float4s
    f32x4* p = (f32x4*)out;
    f32x4 v = p[i];
    int c = (i >> 10) & 255;
    float sc = bnp[c], sh = bnp[256 + c];
    v = v * sc + sh;
    p[i] = v;
}

// ---------------- launch ----------------

extern "C" void kernel_launch(void* const* d_in, const int* in_sizes, int n_in,
                              void* d_out, int out_size, void* d_ws, size_t ws_size,
                              hipStream_t stream) {
    const float* x     = (const float*)d_in[0];
    const float* wgt   = (const float*)d_in[1];
    const float* gamma = (const float*)d_in[2];
    const float* beta  = (const float*)d_in[3];
    float* out = (float*)d_out;

    unsigned short* xp  = (unsigned short*)d_ws;
    unsigned short* Apk = (unsigned short*)((char*)d_ws + XPACK_BYTES);
    float* bnp          = (float*)((char*)d_ws + XPACK_BYTES + APACK_BYTES);

    zero_ws_kernel<<<8024, 256, 0, stream>>>((ushort8*)xp, XPACK_ELEMS / 8);
    pack_x_kernel<<<4096, 256, 0, stream>>>(x, xp);
    pack_w_kernel<<<256, 256, 0, stream>>>(wgt, Apk);
    gemm_kernel<<<512, 256, 0, stream>>>(Apk, xp, out);
    bn_stats_kernel<<<256, 256, 0, stream>>>(out, gamma, beta, bnp);
    bn_apply_kernel<<<8192, 256, 0, stream>>>(out, bnp);
}

// Round 2
// 1297.942 us; speedup vs baseline: 1.2874x; 1.2874x over previous
//
#include <hip/hip_runtime.h>

typedef __attribute__((ext_vector_type(8))) short short8;
typedef __attribute__((ext_vector_type(8))) unsigned short ushort8;
typedef __attribute__((ext_vector_type(4))) float f32x4;

#define K_DIM 70400   // 275 groups * 256 ci ; group g = v*5+kw
#define NT 1100       // K_DIM / 64
#define XROWS 118
#define XCOLS 68
#define BUF 24576     // elems per LDS buffer: A 128x64 (8192) + B 256x64 (16384)
#define BOFF 8192

#define XPACK_ELEMS (8 * XROWS * XCOLS * 256)
#define XPACK_BYTES (XPACK_ELEMS * 2)
#define APACK_ELEMS (256 * K_DIM)
#define APACK_BYTES (APACK_ELEMS * 2)

static __device__ __forceinline__ unsigned short f2bf(float f) {
    unsigned u = __builtin_bit_cast(unsigned, f);
    u += 0x7fffu + ((u >> 16) & 1u);
    return (unsigned short)(u >> 16);
}

static __device__ __forceinline__ void mfma16(f32x4& acc, short8 a, short8 b) {
    asm("v_mfma_f32_16x16x32_bf16 %0, %1, %2, %0" : "+v"(acc) : "v"(a), "v"(b));
}

#define GLOAD_LDS(gp, lp) __builtin_amdgcn_global_load_lds( \
    (const __attribute__((address_space(1))) void*)(gp),    \
    (__attribute__((address_space(3))) void*)(lp), 16, 0, 0)

#define BAR() __builtin_amdgcn_s_barrier()
#define LGKM0() do { asm volatile("s_waitcnt lgkmcnt(0)" ::: "memory"); \
                     __builtin_amdgcn_sched_barrier(0); } while (0)

// ---------------- pack kernels ----------------

__global__ __launch_bounds__(256) void zero_ws_kernel(ushort8* __restrict__ p, int n) {
    int i = blockIdx.x * 256 + threadIdx.x;
    if (i < n) { ushort8 z = {}; p[i] = z; }
}

__global__ __launch_bounds__(256) void pack_x_kernel(const float* __restrict__ x,
                                                     unsigned short* __restrict__ xp) {
    int g = blockIdx.x * 256 + threadIdx.x;
    int xc = g & 63;
    int rest = g >> 6;
    int chunk = rest & 31;
    int br = rest >> 5;
    int xr = br & 63;
    int b  = br >> 6;
    const float* src = x + (long)(b * 256 + chunk * 8) * 4096 + xr * 64 + xc;
    ushort8 o;
#pragma unroll
    for (int e = 0; e < 8; ++e) o[e] = f2bf(src[(long)e * 4096]);
    long off = ((long)((b * XROWS + xr + 25) * XCOLS + (xc + 2))) * 256 + chunk * 8;
    *(ushort8*)(xp + off) = o;
}

__global__ __launch_bounds__(256) void pack_w_kernel(const float* __restrict__ W,
                                                     unsigned short* __restrict__ Apk) {
    int c = blockIdx.x, t = threadIdx.x;
    __shared__ float lw[6400];
    for (int idx = 0; idx < 11; ++idx) {
        const float* src = W + (long)(c * 11 + idx) * 6400;
        for (int e = t; e < 6400; e += 256) lw[e] = src[e];
        __syncthreads();
#pragma unroll 5
        for (int khw = 0; khw < 25; ++khw)
            Apk[(long)c * K_DIM + (idx * 25 + khw) * 256 + t] = f2bf(lw[t * 25 + khw]);
        __syncthreads();
    }
}

// ---------------- GEMM: 256x32768x70400, BM=128 BN=256 BK=64, 8 waves ----------------
__global__ __launch_bounds__(512) void gemm_kernel(const unsigned short* __restrict__ Apk,
                                                   const unsigned short* __restrict__ Xpk,
                                                   float* __restrict__ out) {
    __shared__ unsigned short lds[3 * BUF];   // 144 KiB, triple buffer
    const int t = threadIdx.x;

    // bijective XCD swizzle (256 blocks, 8 XCDs)
    int bid = blockIdx.x;
    int swz = (bid & 7) * 32 + (bid >> 3);
    const int mt = swz >> 7;
    const int nt = swz & 127;
    const int m0 = mt * 128;
    const int n0 = nt * 256;

    const int lane = t & 63;
    const int w = t >> 6;
    const int wm = w >> 2;          // 0..1
    const int wn = w & 3;           // 0..3
    const int lrow = lane & 15;
    const int lsg = lane >> 4;

    // fragment LDS offsets (elems), T2-swizzled: slot ^= row&7
    int offA[4][2], offB[4][2];
#pragma unroll
    for (int m = 0; m < 4; ++m)
#pragma unroll
        for (int kk = 0; kk < 2; ++kk) {
            int sd = kk * 4 + lsg;
            int ra = wm * 64 + m * 16 + lrow;
            offA[m][kk] = ra * 64 + ((sd ^ (ra & 7)) << 3);
            int rb = wn * 64 + m * 16 + lrow;
            offB[m][kk] = BOFF + rb * 64 + ((sd ^ (rb & 7)) << 3);
        }

    // staging: linear LDS dest chunk ch=(row,s) gets global slot s^(row&7)
    const unsigned short* aS[2];
    int aD[2];
#pragma unroll
    for (int r = 0; r < 2; ++r) {
        int ch = r * 512 + t;
        int row = ch >> 3;
        int s = (ch & 7) ^ (row & 7);
        aS[r] = Apk + (long)(m0 + row) * K_DIM + s * 8;
        aD[r] = ch * 8;
    }
    const unsigned short* bS[4];
    int bD[4];
#pragma unroll
    for (int r = 0; r < 4; ++r) {
        int ch = r * 512 + t;
        int row = ch >> 3;
        int s = (ch & 7) ^ (row & 7);
        int n = n0 + row;
        int b = n >> 12, i = (n >> 6) & 63, j = n & 63;
        bS[r] = Xpk + ((long)((b * XROWS + i) * XCOLS + j)) * 256 + s * 8;
        bD[r] = BOFF + ch * 8;
    }

    // prologue: stage tiles 0 and 1, wait for tile 0 only (vmcnt(6))
#pragma unroll
    for (int kt = 0; kt < 2; ++kt) {
        int g = kt >> 2, v = g / 5, kw = g - v * 5;
        int dB = (v * XCOLS + kw) * 256 + ((kt & 3) << 6);
        int qB = kt * BUF;
        GLOAD_LDS(aS[0] + (kt << 6), lds + qB + aD[0]);
        GLOAD_LDS(aS[1] + (kt << 6), lds + qB + aD[1]);
#pragma unroll
        for (int r = 0; r < 4; ++r)
            GLOAD_LDS(bS[r] + dB, lds + qB + bD[r]);
    }
    asm volatile("s_waitcnt vmcnt(6)" ::: "memory");
    BAR();

    f32x4 acc[4][4] = {};
    int qc = 0;
    for (int kt = 0; kt < NT; ++kt) {
        const int kt2 = kt + 2;
        const bool st = kt2 < NT;
        int qs = qc + 2; if (qs >= 3) qs -= 3;
        const int qcB = qc * BUF, qsB = qs * BUF;
        int g = kt2 >> 2, v = g / 5, kw = g - v * 5;
        const int dB2 = (v * XCOLS + kw) * 256 + ((kt2 & 3) << 6);
        const int dA2 = kt2 << 6;

        short8 af[4], b0, b1;
        // ---- phase 0: kk=0, n0/n1
#pragma unroll
        for (int m = 0; m < 4; ++m) af[m] = *(const short8*)(lds + qcB + offA[m][0]);
        b0 = *(const short8*)(lds + qcB + offB[0][0]);
        b1 = *(const short8*)(lds + qcB + offB[1][0]);
        if (st) { GLOAD_LDS(aS[0] + dA2, lds + qsB + aD[0]);
                  GLOAD_LDS(aS[1] + dA2, lds + qsB + aD[1]); }
        BAR(); LGKM0();
        __builtin_amdgcn_s_setprio(1);
#pragma unroll
        for (int m = 0; m < 4; ++m) { mfma16(acc[m][0], af[m], b0); mfma16(acc[m][1], af[m], b1); }
        __builtin_amdgcn_s_setprio(0);
        BAR();
        // ---- phase 1: kk=0, n2/n3
        b0 = *(const short8*)(lds + qcB + offB[2][0]);
        b1 = *(const short8*)(lds + qcB + offB[3][0]);
        if (st) { GLOAD_LDS(bS[0] + dB2, lds + qsB + bD[0]);
                  GLOAD_LDS(bS[1] + dB2, lds + qsB + bD[1]); }
        BAR(); LGKM0();
        __builtin_amdgcn_s_setprio(1);
#pragma unroll
        for (int m = 0; m < 4; ++m) { mfma16(acc[m][2], af[m], b0); mfma16(acc[m][3], af[m], b1); }
        __builtin_amdgcn_s_setprio(0);
        BAR();
        // ---- phase 2: kk=1, n0/n1
#pragma unroll
        for (int m = 0; m < 4; ++m) af[m] = *(const short8*)(lds + qcB + offA[m][1]);
        b0 = *(const short8*)(lds + qcB + offB[0][1]);
        b1 = *(const short8*)(lds + qcB + offB[1][1]);
        if (st) GLOAD_LDS(bS[2] + dB2, lds + qsB + bD[2]);
        BAR(); LGKM0();
        __builtin_amdgcn_s_setprio(1);
#pragma unroll
        for (int m = 0; m < 4; ++m) { mfma16(acc[m][0], af[m], b0); mfma16(acc[m][1], af[m], b1); }
        __builtin_amdgcn_s_setprio(0);
        BAR();
        // ---- phase 3: kk=1, n2/n3 + K-tile boundary (counted vmcnt, never 0 mid-loop)
        b0 = *(const short8*)(lds + qcB + offB[2][1]);
        b1 = *(const short8*)(lds + qcB + offB[3][1]);
        if (st) GLOAD_LDS(bS[3] + dB2, lds + qsB + bD[3]);
        BAR(); LGKM0();
        __builtin_amdgcn_s_setprio(1);
#pragma unroll
        for (int m = 0; m < 4; ++m) { mfma16(acc[m][2], af[m], b0); mfma16(acc[m][3], af[m], b1); }
        __builtin_amdgcn_s_setprio(0);
        if (st) asm volatile("s_waitcnt vmcnt(6)" ::: "memory");
        else    asm volatile("s_waitcnt vmcnt(0)" ::: "memory");
        BAR();
        qc = qc + 1; if (qc == 3) qc = 0;
    }

    // epilogue: C/D row = (lane>>4)*4+reg, col = lane&15  [m89]
    const int b = n0 >> 12;
    const int inb = n0 & 4095;
    float* ob = out + (long)b * 1048576 + inb + wn * 64 + (lane & 15);
#pragma unroll
    for (int m = 0; m < 4; ++m)
#pragma unroll
        for (int qi = 0; qi < 4; ++qi) {
            int row = m0 + wm * 64 + m * 16 + (lane >> 4) * 4 + qi;
            float* orow = ob + (long)row * 4096;
#pragma unroll
            for (int n = 0; n < 4; ++n) orow[n * 16] = acc[m][n][qi];
        }
}

// ---------------- BatchNorm ----------------

__global__ __launch_bounds__(256) void bn_stats_kernel(const float* __restrict__ out,
                                                       const float* __restrict__ gamma,
                                                       const float* __restrict__ beta,
                                                       float* __restrict__ bnp) {
    int c = blockIdx.x, t = threadIdx.x;
    float s = 0.f, q = 0.f;
    for (int b = 0; b < 8; ++b) {
        const float* p = out + (long)b * 1048576 + (long)c * 4096;
        for (int e = t; e < 4096; e += 256) { float v = p[e]; s += v; q += v * v; }
    }
#pragma unroll
    for (int off = 32; off > 0; off >>= 1) { s += __shfl_down(s, off); q += __shfl_down(q, off); }
    __shared__ float ls[4], lq[4];
    int w = t >> 6;
    if ((t & 63) == 0) { ls[w] = s; lq[w] = q; }
    __syncthreads();
    if (t == 0) {
        s = ls[0] + ls[1] + ls[2] + ls[3];
        q = lq[0] + lq[1] + lq[2] + lq[3];
        float mean = s * (1.f / 32768.f);
        float var = q * (1.f / 32768.f) - mean * mean;
        float sc = gamma[c] * rsqrtf(var + 1e-5f);
        bnp[c] = sc;
        bnp[256 + c] = beta[c] - mean * sc;
    }
}

__global__ __launch_bounds__(256) void bn_apply_kernel(float* __restrict__ out,
                                                       const float* __restrict__ bnp) {
    int i = blockIdx.x * 256 + threadIdx.x;
    f32x4* p = (f32x4*)out;
    f32x4 v = p[i];
    int c = (i >> 10) & 255;
    float sc = bnp[c], sh = bnp[256 + c];
    v = v * sc + sh;
    p[i] = v;
}

// ---------------- launch ----------------

extern "C" void kernel_launch(void* const* d_in, const int* in_sizes, int n_in,
                              void* d_out, int out_size, void* d_ws, size_t ws_size,
                              hipStream_t stream) {
    const float* x     = (const float*)d_in[0];
    const float* wgt   = (const float*)d_in[1];
    const float* gamma = (const float*)d_in[2];
    const float* beta  = (const float*)d_in[3];
    float* out = (float*)d_out;

    unsigned short* xp  = (unsigned short*)d_ws;
    unsigned short* Apk = (unsigned short*)((char*)d_ws + XPACK_BYTES);
    float* bnp          = (float*)((char*)d_ws + XPACK_BYTES + APACK_BYTES);

    zero_ws_kernel<<<8024, 256, 0, stream>>>((ushort8*)xp, XPACK_ELEMS / 8);
    pack_x_kernel<<<4096, 256, 0, stream>>>(x, xp);
    pack_w_kernel<<<256, 256, 0, stream>>>(wgt, Apk);
    gemm_kernel<<<256, 512, 0, stream>>>(Apk, xp, out);
    bn_stats_kernel<<<256, 256, 0, stream>>>(out, gamma, beta, bnp);
    bn_apply_kernel<<<8192, 256, 0, stream>>>(out, bnp);
}